// Round 4
// baseline (141.703 us; speedup 1.0000x reference)
//
#include <hip/hip_runtime.h>
#include <hip/hip_bf16.h>
#include <stdint.h>

// KANExpert: out[b,j] = sum_{i,g} basis(x[b,i])[g] * coeff[i,j,g] * scaling[i,j]
// == GEMM M=4096(batch) N=512(out) K=4096(=512 in_dim * 8 basis), bf16 MFMA.
//
// R4: R2/R3 stuck at ~360 TF -- per-CU staging concurrency bound (9 B/cyc/CU
// at 2 blocks/CU vs m97's 16.6 at 3/CU; barrier vmcnt(0) drain un-hidden).
// Fixes: (1) A-tile computed IN-KERNEL from x (1 float -> 8 bf16 basis): kills
// the 32 MB HBM-streamed Ag + its prep write/read; staged bytes/iter 32->20 KB
// with x L2-hot. (2) KSPLIT=8 -> 1024 blocks = 4 blocks/CU. (3) XCD swizzle:
// 1-D grid, col-tile = b&3 == (b%8)&3 so each XCD's L2 holds only 1 MB of Wt.

#define BATCH   4096
#define IN_DIM  512
#define OUT_DIM 512
#define KDIM    (IN_DIM * 8)   // 4096
#define KSPLIT  8
#define KT_PER_SPLIT (KDIM / 64 / KSPLIT)   // 8 K-tiles of BK=64 per split

typedef short short8 __attribute__((ext_vector_type(8)));
typedef float f32x4  __attribute__((ext_vector_type(4)));

// float -> bf16 bits, round-to-nearest-even
__device__ __forceinline__ unsigned short f2bf(float f) {
  union { float f; unsigned int u; } v; v.f = f;
  unsigned int r = v.u + 0x7FFFu + ((v.u >> 16) & 1u);
  return (unsigned short)(r >> 16);
}

// Uniform cubic B-spline window: x in [-1,1), h=0.4. m = floor((x+1)/h) in [0,4].
__device__ __forceinline__ void bspline_win(float xv, float* w, int* mm) {
  float t = (xv + 1.0f) * 2.5f;
  int m = (int)t;
  m = m < 0 ? 0 : (m > 4 ? 4 : m);
  float u  = t - (float)m;
  float u2 = u * u, u3 = u2 * u, om = 1.0f - u;
  w[0] = om * om * om * (1.0f / 6.0f);
  w[1] = (3.0f * u3 - 6.0f * u2 + 4.0f) * (1.0f / 6.0f);
  w[2] = (-3.0f * u3 + 3.0f * u2 + 3.0f * u + 1.0f) * (1.0f / 6.0f);
  w[3] = u3 * (1.0f / 6.0f);
  *mm = m;
}

__device__ __forceinline__ short8 basis_pack8(float xv) {
  float w[4]; int m;
  bspline_win(xv, w, &m);
  short8 h = {};
#pragma unroll
  for (int g = 0; g < 8; ++g) {
    int d = g - m + 3;
    float v = (d == 0) ? w[0] : (d == 1) ? w[1] : (d == 2) ? w[2] : (d == 3) ? w[3] : 0.0f;
    h[g] = (short)f2bf(v);
  }
  return h;
}

__device__ __forceinline__ void async_load16(const void* g, void* l) {
  __builtin_amdgcn_global_load_lds(
      (__attribute__((address_space(1))) void*)(uintptr_t)g,
      (__attribute__((address_space(3))) void*)(unsigned int)(uintptr_t)l,
      16, 0, 0);
}

// ---- precompute W^T only: Wt[j*4096 + i*8 + g] = bf16(coeff[i,j,g]*scaling[i,j])
__global__ void kan_prep(const float* __restrict__ coeff,
                         const float* __restrict__ scaling,
                         unsigned short* __restrict__ Wt) {
  int idx = blockIdx.x * 256 + threadIdx.x;  // i*512 + j
  int i = idx >> 9, j = idx & 511;
  float s = scaling[idx];
  const float4* cp = reinterpret_cast<const float4*>(coeff) + (size_t)idx * 2;
  float4 c0 = cp[0], c1 = cp[1];
  short8 h;
  h[0] = (short)f2bf(c0.x * s); h[1] = (short)f2bf(c0.y * s);
  h[2] = (short)f2bf(c0.z * s); h[3] = (short)f2bf(c0.w * s);
  h[4] = (short)f2bf(c1.x * s); h[5] = (short)f2bf(c1.y * s);
  h[6] = (short)f2bf(c1.z * s); h[7] = (short)f2bf(c1.w * s);
  *reinterpret_cast<short8*>(Wt + (size_t)j * KDIM + i * 8) = h;
}

// ---- fused-A 128x128x64 split-K GEMM ------------------------------------
// 256 thr = 4 waves (2x2), each wave 64x64 = 4x4 tiles of 16x16x32.
// A: basis computed from x in VGPRs, ds_write_b128 into XOR-swizzled As.
// B: global_load_lds from Wt (swizzle applied to the GLOBAL gather address).
// 1-D grid, b = blockIdx.x: col = b&3 (XCD-pinned), row = (b>>2)&31, split = b>>7.
__global__ __launch_bounds__(256, 4)
void kan_gemm_f(const float* __restrict__ x,
                const unsigned short* __restrict__ Wt,
                float* __restrict__ out) {
  __shared__ unsigned short As[128 * 64];   // 16 KB
  __shared__ unsigned short Bs[128 * 64];   // 16 KB

  const int tid  = threadIdx.x;
  const int lane = tid & 63;
  const int wid  = tid >> 6;
  const int wm = wid >> 1, wn = wid & 1;
  const int ln = lane & 15, quad = lane >> 4;

  const int b    = blockIdx.x;
  const int col0 = (b & 3) * 128;           // XCD g hosts only col-tile g&3
  const int row0 = ((b >> 2) & 31) * 128;
  const int kt0  = (b >> 7) * KT_PER_SPLIT;

  f32x4 acc[4][4] = {};

  const int lr = lane >> 3;                 // B staging: row offset in 8-row inst
  const int cg = (lane & 7) ^ lr;           // swizzled 16B chunk to fetch

  const int arow  = tid >> 1;               // 0..127: A row handled by this thread
  const int ihalf = (tid & 1) * 4;          // which 4 of the 8 i-values

  for (int kt = kt0; kt < kt0 + KT_PER_SPLIT; ++kt) {
    const int k0 = kt * 64;
    // B: 16 KB via 4 async insts/wave
#pragma unroll
    for (int t = 0; t < 4; ++t) {
      const int rbase = wid * 32 + t * 8;                      // wave-uniform
      const unsigned short* gb = Wt + (size_t)(col0 + rbase + lr) * KDIM + k0 + cg * 8;
      async_load16(gb, &Bs[rbase * 64]);
    }
    // A: basis on the fly. Thread covers (arow, i0+ihalf .. +3), one float4 x read.
    float4 xv = *reinterpret_cast<const float4*>(
        x + (size_t)(row0 + arow) * IN_DIM + kt * 8 + ihalf);
#pragma unroll
    for (int q = 0; q < 4; ++q) {
      float xq = (q == 0) ? xv.x : (q == 1) ? xv.y : (q == 2) ? xv.z : xv.w;
      short8 h = basis_pack8(xq);
      const int slot = (ihalf + q) ^ (arow & 7);
      *reinterpret_cast<short8*>(&As[arow * 64 + slot * 8]) = h;
    }
    __syncthreads();   // drains vmcnt (B) + lgkmcnt (A ds_writes)

#pragma unroll
    for (int kk = 0; kk < 2; ++kk) {
      short8 af[4], bfr[4];
#pragma unroll
      for (int mt = 0; mt < 4; ++mt) {
        const int r    = wm * 64 + mt * 16 + ln;
        const int slot = (kk * 4 + quad) ^ (r & 7);
        af[mt] = *reinterpret_cast<const short8*>(&As[r * 64 + slot * 8]);
      }
#pragma unroll
      for (int nt = 0; nt < 4; ++nt) {
        const int c    = wn * 64 + nt * 16 + ln;
        const int slot = (kk * 4 + quad) ^ (c & 7);
        bfr[nt] = *reinterpret_cast<const short8*>(&Bs[c * 64 + slot * 8]);
      }
#pragma unroll
      for (int mt = 0; mt < 4; ++mt)
#pragma unroll
        for (int nt = 0; nt < 4; ++nt)
          acc[mt][nt] = __builtin_amdgcn_mfma_f32_16x16x32_bf16(af[mt], bfr[nt], acc[mt][nt], 0, 0, 0);
    }
    __syncthreads();
  }

  // C/D layout: col = lane&15, row = quad*4 + reg
#pragma unroll
  for (int mt = 0; mt < 4; ++mt)
#pragma unroll
    for (int nt = 0; nt < 4; ++nt) {
      const int col = col0 + wn * 64 + nt * 16 + ln;
#pragma unroll
      for (int rr = 0; rr < 4; ++rr) {
        const int row = row0 + wm * 64 + mt * 16 + quad * 4 + rr;
        unsafeAtomicAdd(&out[(size_t)row * OUT_DIM + col], acc[mt][nt][rr]);
      }
    }
}

// ---- fallback (no ws): on-the-fly staging, 64-tile, direct store ---------
__global__ __launch_bounds__(256, 2)
void kan_gemm_fb(const float* __restrict__ x, const float* __restrict__ coeff,
                 const float* __restrict__ scaling, float* __restrict__ out) {
  __shared__ unsigned short As[64 * 64];
  __shared__ unsigned short Bs[64 * 64];

  const int tid  = threadIdx.x;
  const int lane = tid & 63;
  const int wid  = tid >> 6;
  const int wm = wid >> 1, wn = wid & 1;
  const int ln = lane & 15, quad = lane >> 4;
  const int row0 = blockIdx.y * 64;
  const int col0 = blockIdx.x * 64;

  f32x4 acc[2][2] = {};

  for (int kt = 0; kt < KDIM / 64; ++kt) {
#pragma unroll
    for (int pp = 0; pp < 2; ++pp) {
      const int p  = tid + pp * 256;
      const int rn = p & 63;
      const int il = p >> 6;
      const int sw = ((il ^ (rn & 7)) * 8);
      short8 ha = basis_pack8(x[(size_t)(row0 + rn) * IN_DIM + kt * 8 + il]);
      *reinterpret_cast<short8*>(&As[rn * 64 + sw]) = ha;
      const float* cbase = coeff + (size_t)(kt * 8 + il) * 4096 + (size_t)(col0 + rn) * 8;
      float4 c0 = reinterpret_cast<const float4*>(cbase)[0];
      float4 c1 = reinterpret_cast<const float4*>(cbase)[1];
      float s = scaling[(size_t)(kt * 8 + il) * OUT_DIM + col0 + rn];
      short8 hb;
      hb[0] = (short)f2bf(c0.x * s); hb[1] = (short)f2bf(c0.y * s);
      hb[2] = (short)f2bf(c0.z * s); hb[3] = (short)f2bf(c0.w * s);
      hb[4] = (short)f2bf(c1.x * s); hb[5] = (short)f2bf(c1.y * s);
      hb[6] = (short)f2bf(c1.z * s); hb[7] = (short)f2bf(c1.w * s);
      *reinterpret_cast<short8*>(&Bs[rn * 64 + sw]) = hb;
    }
    __syncthreads();
#pragma unroll
    for (int kk = 0; kk < 2; ++kk) {
      short8 af[2], bfr[2];
#pragma unroll
      for (int mt = 0; mt < 2; ++mt) {
        const int r  = wm * 32 + mt * 16 + ln;
        const int pc = (kk * 4 + quad) ^ (r & 7);
        af[mt] = *reinterpret_cast<const short8*>(&As[r * 64 + pc * 8]);
      }
#pragma unroll
      for (int nt = 0; nt < 2; ++nt) {
        const int c  = wn * 32 + nt * 16 + ln;
        const int pc = (kk * 4 + quad) ^ (c & 7);
        bfr[nt] = *reinterpret_cast<const short8*>(&Bs[c * 64 + pc * 8]);
      }
#pragma unroll
      for (int mt = 0; mt < 2; ++mt)
#pragma unroll
        for (int nt = 0; nt < 2; ++nt)
          acc[mt][nt] = __builtin_amdgcn_mfma_f32_16x16x32_bf16(af[mt], bfr[nt], acc[mt][nt], 0, 0, 0);
    }
    __syncthreads();
  }
#pragma unroll
  for (int mt = 0; mt < 2; ++mt)
#pragma unroll
    for (int nt = 0; nt < 2; ++nt) {
      const int col = col0 + wn * 32 + nt * 16 + ln;
#pragma unroll
      for (int r = 0; r < 4; ++r) {
        const int row = row0 + wm * 32 + mt * 16 + quad * 4 + r;
        out[(size_t)row * OUT_DIM + col] = acc[mt][nt][r];
      }
    }
}

// ---- launch ------------------------------------------------------------
extern "C" void kernel_launch(void* const* d_in, const int* in_sizes, int n_in,
                              void* d_out, int out_size, void* d_ws, size_t ws_size,
                              hipStream_t stream) {
  const float* x       = (const float*)d_in[0];
  const float* coeff   = (const float*)d_in[1];
  const float* scaling = (const float*)d_in[2];
  float* out = (float*)d_out;

  const size_t needW = (size_t)OUT_DIM * KDIM * 2;   // 4 MB bf16 W^T

  if (ws_size >= needW) {
    unsigned short* Wt = (unsigned short*)d_ws;
    hipMemsetAsync(out, 0, (size_t)out_size * sizeof(float), stream);
    kan_prep<<<(IN_DIM * OUT_DIM) / 256, 256, 0, stream>>>(coeff, scaling, Wt);
    kan_gemm_f<<<(OUT_DIM / 128) * (BATCH / 128) * KSPLIT, 256, 0, stream>>>(x, Wt, out);
  } else {
    kan_gemm_fb<<<dim3(OUT_DIM / 64, BATCH / 64), 256, 0, stream>>>(x, coeff, scaling, out);
  }
}

// Round 5
// 113.869 us; speedup vs baseline: 1.2444x; 1.2444x over previous
//
#include <hip/hip_runtime.h>
#include <hip/hip_bf16.h>
#include <stdint.h>

// KANExpert: out[b,j] = sum_{i,g} basis(x[b,i])[g] * coeff[i,j,g] * scaling[i,j]
// == GEMM M=4096(batch) N=512(out) K=4096(=512 in_dim * 8 basis), bf16 MFMA.
//
// R5: R1 was EA-traffic-bound (dur == FETCH/3.3 TB/s; Ag re-read 8x because
// row-major grid put same-row-tile blocks on 8 different XCDs). R4 showed
// device-scope atomics are EA RMWs -- dropped. Fix: 64-tile full-K GEMM,
// col-major 1-D grid (b = c*64 + r) so all 8 col-tiles of row-tile r land on
// XCD r%8: A re-reads become per-XCD L2 hits. Direct stores, no split-K.

#define BATCH   4096
#define IN_DIM  512
#define OUT_DIM 512
#define KDIM    (IN_DIM * 8)   // 4096

typedef short short8 __attribute__((ext_vector_type(8)));
typedef float f32x4  __attribute__((ext_vector_type(4)));

// float -> bf16 bits, round-to-nearest-even
__device__ __forceinline__ unsigned short f2bf(float f) {
  union { float f; unsigned int u; } v; v.f = f;
  unsigned int r = v.u + 0x7FFFu + ((v.u >> 16) & 1u);
  return (unsigned short)(r >> 16);
}

// Uniform cubic B-spline window: x in [-1,1), h=0.4. m = floor((x+1)/h) in [0,4].
__device__ __forceinline__ void bspline_win(float xv, float* w, int* mm) {
  float t = (xv + 1.0f) * 2.5f;
  int m = (int)t;
  m = m < 0 ? 0 : (m > 4 ? 4 : m);
  float u  = t - (float)m;
  float u2 = u * u, u3 = u2 * u, om = 1.0f - u;
  w[0] = om * om * om * (1.0f / 6.0f);
  w[1] = (3.0f * u3 - 6.0f * u2 + 4.0f) * (1.0f / 6.0f);
  w[2] = (-3.0f * u3 + 3.0f * u2 + 3.0f * u + 1.0f) * (1.0f / 6.0f);
  w[3] = u3 * (1.0f / 6.0f);
  *mm = m;
}

__device__ __forceinline__ short8 basis_pack8(float xv) {
  float w[4]; int m;
  bspline_win(xv, w, &m);
  short8 h = {};
#pragma unroll
  for (int g = 0; g < 8; ++g) {
    int d = g - m + 3;
    float v = (d == 0) ? w[0] : (d == 1) ? w[1] : (d == 2) ? w[2] : (d == 3) ? w[3] : 0.0f;
    h[g] = (short)f2bf(v);
  }
  return h;
}

__device__ __forceinline__ void async_load16(const void* g, void* l) {
  __builtin_amdgcn_global_load_lds(
      (__attribute__((address_space(1))) void*)(uintptr_t)g,
      (__attribute__((address_space(3))) void*)(unsigned int)(uintptr_t)l,
      16, 0, 0);
}

// ---- fused precompute: basis (blocks 0..8191) + W^T pack (blocks 8192..9215)
__global__ void kan_prep(const float* __restrict__ x,
                         const float* __restrict__ coeff,
                         const float* __restrict__ scaling,
                         unsigned short* __restrict__ Ag,
                         unsigned short* __restrict__ Wt) {
  const int b = blockIdx.x;
  if (b < (BATCH * IN_DIM) / 256) {
    int idx = b * 256 + threadIdx.x;
    short8 h = basis_pack8(x[idx]);
    *reinterpret_cast<short8*>(Ag + (size_t)idx * 8) = h;
  } else {
    int idx = (b - (BATCH * IN_DIM) / 256) * 256 + threadIdx.x;  // i*512 + j
    int i = idx >> 9, j = idx & 511;
    float s = scaling[idx];
    const float4* cp = reinterpret_cast<const float4*>(coeff) + (size_t)idx * 2;
    float4 c0 = cp[0], c1 = cp[1];
    short8 h;
    h[0] = (short)f2bf(c0.x * s); h[1] = (short)f2bf(c0.y * s);
    h[2] = (short)f2bf(c0.z * s); h[3] = (short)f2bf(c0.w * s);
    h[4] = (short)f2bf(c1.x * s); h[5] = (short)f2bf(c1.y * s);
    h[6] = (short)f2bf(c1.z * s); h[7] = (short)f2bf(c1.w * s);
    *reinterpret_cast<short8*>(Wt + (size_t)j * KDIM + i * 8) = h;
  }
}

// ---- full-K 64x64x64 GEMM, XCD-aligned col-major grid --------------------
// 256 thr = 4 waves (2x2), wave tile 32x32 (2x2 of 16x16x32). 1-D grid of
// 512 blocks: r = b % 64 (row-tile), c = b / 64 (col-tile). Round-robin
// dispatch -> XCD = b % 8 = r % 8, so all col-tiles of a row-tile share one
// XCD's L2; 8 concurrent row-slices/XCD x 0.5 MB = 4 MB = L2 size.
// LDS rows XOR-swizzled in 16B chunks (swizzle on the GLOBAL gather address
// so global_load_lds LDS writes stay lane-contiguous); 0 bank conflicts.
__global__ __launch_bounds__(256, 2)
void kan_gemm_x(const unsigned short* __restrict__ Ag,
                const unsigned short* __restrict__ Wt,
                float* __restrict__ out) {
  __shared__ unsigned short As[64 * 64];
  __shared__ unsigned short Bs[64 * 64];

  const int tid  = threadIdx.x;
  const int lane = tid & 63;
  const int wid  = tid >> 6;
  const int wm = wid >> 1, wn = wid & 1;
  const int ln = lane & 15, quad = lane >> 4;

  const int b    = blockIdx.x;
  const int row0 = (b & 63) * 64;           // b%64: row-tile (XCD-pinning key)
  const int col0 = (b >> 6) * 64;           // b/64: col-tile

  f32x4 acc[2][2] = {};

  const int lr = lane >> 3;
  const int cg = (lane & 7) ^ lr;

  for (int kt = 0; kt < KDIM / 64; ++kt) {
    const int k0 = kt * 64;
#pragma unroll
    for (int t = 0; t < 2; ++t) {
      const int rbase = wid * 16 + t * 8;                       // wave-uniform
      const unsigned short* ga = Ag + (size_t)(row0 + rbase + lr) * KDIM + k0 + cg * 8;
      async_load16(ga, &As[rbase * 64]);
      const unsigned short* gb = Wt + (size_t)(col0 + rbase + lr) * KDIM + k0 + cg * 8;
      async_load16(gb, &Bs[rbase * 64]);
    }
    __syncthreads();

#pragma unroll
    for (int kk = 0; kk < 2; ++kk) {
      short8 af[2], bfr[2];
#pragma unroll
      for (int mt = 0; mt < 2; ++mt) {
        const int r  = wm * 32 + mt * 16 + ln;
        const int pc = (kk * 4 + quad) ^ (r & 7);
        af[mt] = *reinterpret_cast<const short8*>(&As[r * 64 + pc * 8]);
      }
#pragma unroll
      for (int nt = 0; nt < 2; ++nt) {
        const int c  = wn * 32 + nt * 16 + ln;
        const int pc = (kk * 4 + quad) ^ (c & 7);
        bfr[nt] = *reinterpret_cast<const short8*>(&Bs[c * 64 + pc * 8]);
      }
#pragma unroll
      for (int mt = 0; mt < 2; ++mt)
#pragma unroll
        for (int nt = 0; nt < 2; ++nt)
          acc[mt][nt] = __builtin_amdgcn_mfma_f32_16x16x32_bf16(af[mt], bfr[nt], acc[mt][nt], 0, 0, 0);
    }
    __syncthreads();
  }

  // C/D layout: col = lane&15, row = quad*4 + reg
#pragma unroll
  for (int mt = 0; mt < 2; ++mt)
#pragma unroll
    for (int nt = 0; nt < 2; ++nt) {
      const int col = col0 + wn * 32 + nt * 16 + ln;
#pragma unroll
      for (int r = 0; r < 4; ++r) {
        const int row = row0 + wm * 32 + mt * 16 + quad * 4 + r;
        out[(size_t)row * OUT_DIM + col] = acc[mt][nt][r];
      }
    }
}

// ---- fallback (no ws): on-the-fly staging, 64-tile, direct store ---------
__global__ __launch_bounds__(256, 2)
void kan_gemm_fb(const float* __restrict__ x, const float* __restrict__ coeff,
                 const float* __restrict__ scaling, float* __restrict__ out) {
  __shared__ unsigned short As[64 * 64];
  __shared__ unsigned short Bs[64 * 64];

  const int tid  = threadIdx.x;
  const int lane = tid & 63;
  const int wid  = tid >> 6;
  const int wm = wid >> 1, wn = wid & 1;
  const int ln = lane & 15, quad = lane >> 4;
  const int row0 = blockIdx.y * 64;
  const int col0 = blockIdx.x * 64;

  f32x4 acc[2][2] = {};

  for (int kt = 0; kt < KDIM / 64; ++kt) {
#pragma unroll
    for (int pp = 0; pp < 2; ++pp) {
      const int p  = tid + pp * 256;
      const int rn = p & 63;
      const int il = p >> 6;
      const int sw = ((il ^ (rn & 7)) * 8);
      short8 ha = basis_pack8(x[(size_t)(row0 + rn) * IN_DIM + kt * 8 + il]);
      *reinterpret_cast<short8*>(&As[rn * 64 + sw]) = ha;
      const float* cbase = coeff + (size_t)(kt * 8 + il) * 4096 + (size_t)(col0 + rn) * 8;
      float4 c0 = reinterpret_cast<const float4*>(cbase)[0];
      float4 c1 = reinterpret_cast<const float4*>(cbase)[1];
      float s = scaling[(size_t)(kt * 8 + il) * OUT_DIM + col0 + rn];
      short8 hb;
      hb[0] = (short)f2bf(c0.x * s); hb[1] = (short)f2bf(c0.y * s);
      hb[2] = (short)f2bf(c0.z * s); hb[3] = (short)f2bf(c0.w * s);
      hb[4] = (short)f2bf(c1.x * s); hb[5] = (short)f2bf(c1.y * s);
      hb[6] = (short)f2bf(c1.z * s); hb[7] = (short)f2bf(c1.w * s);
      *reinterpret_cast<short8*>(&Bs[rn * 64 + sw]) = hb;
    }
    __syncthreads();
#pragma unroll
    for (int kk = 0; kk < 2; ++kk) {
      short8 af[2], bfr[2];
#pragma unroll
      for (int mt = 0; mt < 2; ++mt) {
        const int r  = wm * 32 + mt * 16 + ln;
        const int pc = (kk * 4 + quad) ^ (r & 7);
        af[mt] = *reinterpret_cast<const short8*>(&As[r * 64 + pc * 8]);
      }
#pragma unroll
      for (int nt = 0; nt < 2; ++nt) {
        const int c  = wn * 32 + nt * 16 + ln;
        const int pc = (kk * 4 + quad) ^ (c & 7);
        bfr[nt] = *reinterpret_cast<const short8*>(&Bs[c * 64 + pc * 8]);
      }
#pragma unroll
      for (int mt = 0; mt < 2; ++mt)
#pragma unroll
        for (int nt = 0; nt < 2; ++nt)
          acc[mt][nt] = __builtin_amdgcn_mfma_f32_16x16x32_bf16(af[mt], bfr[nt], acc[mt][nt], 0, 0, 0);
    }
    __syncthreads();
  }
#pragma unroll
  for (int mt = 0; mt < 2; ++mt)
#pragma unroll
    for (int nt = 0; nt < 2; ++nt) {
      const int col = col0 + wn * 32 + nt * 16 + ln;
#pragma unroll
      for (int r = 0; r < 4; ++r) {
        const int row = row0 + wm * 32 + mt * 16 + quad * 4 + r;
        out[(size_t)row * OUT_DIM + col] = acc[mt][nt][r];
      }
    }
}

// ---- launch ------------------------------------------------------------
extern "C" void kernel_launch(void* const* d_in, const int* in_sizes, int n_in,
                              void* d_out, int out_size, void* d_ws, size_t ws_size,
                              hipStream_t stream) {
  const float* x       = (const float*)d_in[0];
  const float* coeff   = (const float*)d_in[1];
  const float* scaling = (const float*)d_in[2];
  float* out = (float*)d_out;

  const size_t needA = (size_t)BATCH * KDIM * 2;     // 32 MB bf16 basis
  const size_t needW = (size_t)OUT_DIM * KDIM * 2;   // 4 MB bf16 W^T

  if (ws_size >= needA + needW) {
    unsigned short* Ag = (unsigned short*)d_ws;
    unsigned short* Wt = (unsigned short*)((char*)d_ws + needA);
    kan_prep<<<(BATCH * IN_DIM) / 256 + (IN_DIM * OUT_DIM) / 256, 256, 0, stream>>>(
        x, coeff, scaling, Ag, Wt);
    kan_gemm_x<<<(BATCH / 64) * (OUT_DIM / 64), 256, 0, stream>>>(Ag, Wt, out);
  } else {
    kan_gemm_fb<<<dim3(OUT_DIM / 64, BATCH / 64), 256, 0, stream>>>(x, coeff, scaling, out);
  }
}

// Round 6
// 98.748 us; speedup vs baseline: 1.4350x; 1.1531x over previous
//
#include <hip/hip_runtime.h>
#include <hip/hip_bf16.h>
#include <stdint.h>

// KANExpert: out[b,j] = sum_{i,g} basis(x[b,i])[g] * coeff[i,j,g] * scaling[i,j]
// == GEMM M=4096(batch) N=512(out) K=4096(=512 in_dim * 8 basis), bf16 MFMA.
//
// R6: R5's gemm (~40 us by subtraction) is latency-serial: 2-barrier K-loop
// exposes one full load latency per K-iter at 2 blocks/CU. Restructure:
// depth-3 LDS ring (48 KB), raw s_barrier + manual s_waitcnt vmcnt(8) so
// tiles k+1,k+2 stay in flight across the barrier (AITER-style). Keep R5's
// XCD col-major grid (row-tile pinned to XCD -> A re-reads are L2 hits).

#define BATCH   4096
#define IN_DIM  512
#define OUT_DIM 512
#define KDIM    (IN_DIM * 8)   // 4096
#define NKT     (KDIM / 64)    // 64 K-tiles

typedef short short8 __attribute__((ext_vector_type(8)));
typedef float f32x4  __attribute__((ext_vector_type(4)));

// gfx9 s_waitcnt immediates: vmcnt low4 | expcnt<<4 | lgkmcnt<<8 (vmcnt hi @14)
#define WAIT_VM8 0xF78   // vmcnt(8), lgkm/exp unconstrained
#define WAIT_VM4 0xF74   // vmcnt(4)
#define WAIT_VM0 0xF70   // vmcnt(0)

// float -> bf16 bits, round-to-nearest-even
__device__ __forceinline__ unsigned short f2bf(float f) {
  union { float f; unsigned int u; } v; v.f = f;
  unsigned int r = v.u + 0x7FFFu + ((v.u >> 16) & 1u);
  return (unsigned short)(r >> 16);
}

// Uniform cubic B-spline window: x in [-1,1), h=0.4. m = floor((x+1)/h) in [0,4].
__device__ __forceinline__ void bspline_win(float xv, float* w, int* mm) {
  float t = (xv + 1.0f) * 2.5f;
  int m = (int)t;
  m = m < 0 ? 0 : (m > 4 ? 4 : m);
  float u  = t - (float)m;
  float u2 = u * u, u3 = u2 * u, om = 1.0f - u;
  w[0] = om * om * om * (1.0f / 6.0f);
  w[1] = (3.0f * u3 - 6.0f * u2 + 4.0f) * (1.0f / 6.0f);
  w[2] = (-3.0f * u3 + 3.0f * u2 + 3.0f * u + 1.0f) * (1.0f / 6.0f);
  w[3] = u3 * (1.0f / 6.0f);
  *mm = m;
}

__device__ __forceinline__ short8 basis_pack8(float xv) {
  float w[4]; int m;
  bspline_win(xv, w, &m);
  short8 h = {};
#pragma unroll
  for (int g = 0; g < 8; ++g) {
    int d = g - m + 3;
    float v = (d == 0) ? w[0] : (d == 1) ? w[1] : (d == 2) ? w[2] : (d == 3) ? w[3] : 0.0f;
    h[g] = (short)f2bf(v);
  }
  return h;
}

__device__ __forceinline__ void async_load16(const void* g, void* l) {
  __builtin_amdgcn_global_load_lds(
      (__attribute__((address_space(1))) void*)(uintptr_t)g,
      (__attribute__((address_space(3))) void*)(unsigned int)(uintptr_t)l,
      16, 0, 0);
}

// ---- fused precompute: basis (blocks 0..8191) + W^T pack (8192..9215) ----
__global__ void kan_prep(const float* __restrict__ x,
                         const float* __restrict__ coeff,
                         const float* __restrict__ scaling,
                         unsigned short* __restrict__ Ag,
                         unsigned short* __restrict__ Wt) {
  const int b = blockIdx.x;
  if (b < (BATCH * IN_DIM) / 256) {
    int idx = b * 256 + threadIdx.x;
    short8 h = basis_pack8(x[idx]);
    *reinterpret_cast<short8*>(Ag + (size_t)idx * 8) = h;
  } else {
    int idx = (b - (BATCH * IN_DIM) / 256) * 256 + threadIdx.x;  // i*512 + j
    int i = idx >> 9, j = idx & 511;
    float s = scaling[idx];
    const float4* cp = reinterpret_cast<const float4*>(coeff) + (size_t)idx * 2;
    float4 c0 = cp[0], c1 = cp[1];
    short8 h;
    h[0] = (short)f2bf(c0.x * s); h[1] = (short)f2bf(c0.y * s);
    h[2] = (short)f2bf(c0.z * s); h[3] = (short)f2bf(c0.w * s);
    h[4] = (short)f2bf(c1.x * s); h[5] = (short)f2bf(c1.y * s);
    h[6] = (short)f2bf(c1.z * s); h[7] = (short)f2bf(c1.w * s);
    *reinterpret_cast<short8*>(Wt + (size_t)j * KDIM + i * 8) = h;
  }
}

// ---- pipelined 64x64x64 GEMM, depth-3 LDS ring ---------------------------
// 256 thr = 4 waves (2x2), wave tile 32x32 (2x2 of 16x16x32). 1-D grid of
// 512 blocks: row-tile = b%64 (XCD = b%8 -> same-row blocks share one L2),
// col-tile = b/64. Protocol per iter k (stage st = k%3):
//   s_waitcnt vmcnt(8)  -- own 4 loads of tile k retired; k+1,k+2 in flight
//   s_barrier           -- all waves' tile-k loads retired
//   compute(st)
//   s_barrier           -- stage st free to recycle
//   issue tile k+3 -> st
__global__ __launch_bounds__(256, 2)
void kan_gemm_p(const unsigned short* __restrict__ Ag,
                const unsigned short* __restrict__ Wt,
                float* __restrict__ out) {
  __shared__ unsigned short As[3][64 * 64];   // 3 x 8 KB
  __shared__ unsigned short Bs[3][64 * 64];   // 3 x 8 KB

  const int tid  = threadIdx.x;
  const int lane = tid & 63;
  const int wid  = tid >> 6;
  const int wm = wid >> 1, wn = wid & 1;
  const int ln = lane & 15, quad = lane >> 4;

  const int b    = blockIdx.x;
  const int row0 = (b & 63) * 64;           // XCD-pinning key
  const int col0 = (b >> 6) * 64;

  f32x4 acc[2][2] = {};

  const int lr = lane >> 3;                 // staging row within 8-row inst
  const int cg = (lane & 7) ^ lr;           // XOR-swizzled 16B chunk to fetch

  const unsigned short* aRow = Ag + (size_t)(row0 + wid * 16 + lr) * KDIM + cg * 8;
  const unsigned short* bRow = Wt + (size_t)(col0 + wid * 16 + lr) * KDIM + cg * 8;

  // issue tile kt's 4 async loads into stage st
  auto issue = [&](int kt, int st) {
    const int k0 = kt * 64;
#pragma unroll
    for (int t = 0; t < 2; ++t) {
      const int rbase = wid * 16 + t * 8;                       // wave-uniform
      async_load16(aRow + (size_t)t * 8 * KDIM + k0, &As[st][rbase * 64]);
      async_load16(bRow + (size_t)t * 8 * KDIM + k0, &Bs[st][rbase * 64]);
    }
  };

  auto compute = [&](int st) {
#pragma unroll
    for (int kk = 0; kk < 2; ++kk) {
      short8 af[2], bfr[2];
#pragma unroll
      for (int mt = 0; mt < 2; ++mt) {
        const int r    = wm * 32 + mt * 16 + ln;
        const int slot = (kk * 4 + quad) ^ (r & 7);
        af[mt] = *reinterpret_cast<const short8*>(&As[st][r * 64 + slot * 8]);
      }
#pragma unroll
      for (int nt = 0; nt < 2; ++nt) {
        const int c    = wn * 32 + nt * 16 + ln;
        const int slot = (kk * 4 + quad) ^ (c & 7);
        bfr[nt] = *reinterpret_cast<const short8*>(&Bs[st][c * 64 + slot * 8]);
      }
#pragma unroll
      for (int mt = 0; mt < 2; ++mt)
#pragma unroll
        for (int nt = 0; nt < 2; ++nt)
          acc[mt][nt] = __builtin_amdgcn_mfma_f32_16x16x32_bf16(af[mt], bfr[nt], acc[mt][nt], 0, 0, 0);
    }
  };

  issue(0, 0); issue(1, 1); issue(2, 2);

  int st = 0;
  for (int kt = 0; kt < NKT - 3; ++kt) {
    __builtin_amdgcn_s_waitcnt(WAIT_VM8);
    __builtin_amdgcn_s_barrier();
    compute(st);
    __builtin_amdgcn_s_barrier();
    issue(kt + 3, st);
    st = (st == 2) ? 0 : st + 1;
  }
  // tail: tiles NKT-3, NKT-2, NKT-1 (stages st, st+1, st+2 mod 3)
  __builtin_amdgcn_s_waitcnt(WAIT_VM8);
  __builtin_amdgcn_s_barrier();
  compute(st);
  st = (st == 2) ? 0 : st + 1;
  __builtin_amdgcn_s_waitcnt(WAIT_VM4);
  __builtin_amdgcn_s_barrier();
  compute(st);
  st = (st == 2) ? 0 : st + 1;
  __builtin_amdgcn_s_waitcnt(WAIT_VM0);
  __builtin_amdgcn_s_barrier();
  compute(st);

  // C/D layout: col = lane&15, row = quad*4 + reg
#pragma unroll
  for (int mt = 0; mt < 2; ++mt)
#pragma unroll
    for (int nt = 0; nt < 2; ++nt) {
      const int col = col0 + wn * 32 + nt * 16 + ln;
#pragma unroll
      for (int r = 0; r < 4; ++r) {
        const int row = row0 + wm * 32 + mt * 16 + quad * 4 + r;
        out[(size_t)row * OUT_DIM + col] = acc[mt][nt][r];
      }
    }
}

// ---- fallback (no ws): on-the-fly staging, 64-tile, direct store ---------
__global__ __launch_bounds__(256, 2)
void kan_gemm_fb(const float* __restrict__ x, const float* __restrict__ coeff,
                 const float* __restrict__ scaling, float* __restrict__ out) {
  __shared__ unsigned short As[64 * 64];
  __shared__ unsigned short Bs[64 * 64];

  const int tid  = threadIdx.x;
  const int lane = tid & 63;
  const int wid  = tid >> 6;
  const int wm = wid >> 1, wn = wid & 1;
  const int ln = lane & 15, quad = lane >> 4;
  const int row0 = blockIdx.y * 64;
  const int col0 = blockIdx.x * 64;

  f32x4 acc[2][2] = {};

  for (int kt = 0; kt < KDIM / 64; ++kt) {
#pragma unroll
    for (int pp = 0; pp < 2; ++pp) {
      const int p  = tid + pp * 256;
      const int rn = p & 63;
      const int il = p >> 6;
      const int sw = ((il ^ (rn & 7)) * 8);
      short8 ha = basis_pack8(x[(size_t)(row0 + rn) * IN_DIM + kt * 8 + il]);
      *reinterpret_cast<short8*>(&As[rn * 64 + sw]) = ha;
      const float* cbase = coeff + (size_t)(kt * 8 + il) * 4096 + (size_t)(col0 + rn) * 8;
      float4 c0 = reinterpret_cast<const float4*>(cbase)[0];
      float4 c1 = reinterpret_cast<const float4*>(cbase)[1];
      float s = scaling[(size_t)(kt * 8 + il) * OUT_DIM + col0 + rn];
      short8 hb;
      hb[0] = (short)f2bf(c0.x * s); hb[1] = (short)f2bf(c0.y * s);
      hb[2] = (short)f2bf(c0.z * s); hb[3] = (short)f2bf(c0.w * s);
      hb[4] = (short)f2bf(c1.x * s); hb[5] = (short)f2bf(c1.y * s);
      hb[6] = (short)f2bf(c1.z * s); hb[7] = (short)f2bf(c1.w * s);
      *reinterpret_cast<short8*>(&Bs[rn * 64 + sw]) = hb;
    }
    __syncthreads();
#pragma unroll
    for (int kk = 0; kk < 2; ++kk) {
      short8 af[2], bfr[2];
#pragma unroll
      for (int mt = 0; mt < 2; ++mt) {
        const int r  = wm * 32 + mt * 16 + ln;
        const int pc = (kk * 4 + quad) ^ (r & 7);
        af[mt] = *reinterpret_cast<const short8*>(&As[r * 64 + pc * 8]);
      }
#pragma unroll
      for (int nt = 0; nt < 2; ++nt) {
        const int c  = wn * 32 + nt * 16 + ln;
        const int pc = (kk * 4 + quad) ^ (c & 7);
        bfr[nt] = *reinterpret_cast<const short8*>(&Bs[c * 64 + pc * 8]);
      }
#pragma unroll
      for (int mt = 0; mt < 2; ++mt)
#pragma unroll
        for (int nt = 0; nt < 2; ++nt)
          acc[mt][nt] = __builtin_amdgcn_mfma_f32_16x16x32_bf16(af[mt], bfr[nt], acc[mt][nt], 0, 0, 0);
    }
    __syncthreads();
  }
#pragma unroll
  for (int mt = 0; mt < 2; ++mt)
#pragma unroll
    for (int nt = 0; nt < 2; ++nt) {
      const int col = col0 + wn * 32 + nt * 16 + ln;
#pragma unroll
      for (int r = 0; r < 4; ++r) {
        const int row = row0 + wm * 32 + mt * 16 + quad * 4 + r;
        out[(size_t)row * OUT_DIM + col] = acc[mt][nt][r];
      }
    }
}

// ---- launch ------------------------------------------------------------
extern "C" void kernel_launch(void* const* d_in, const int* in_sizes, int n_in,
                              void* d_out, int out_size, void* d_ws, size_t ws_size,
                              hipStream_t stream) {
  const float* x       = (const float*)d_in[0];
  const float* coeff   = (const float*)d_in[1];
  const float* scaling = (const float*)d_in[2];
  float* out = (float*)d_out;

  const size_t needA = (size_t)BATCH * KDIM * 2;     // 32 MB bf16 basis
  const size_t needW = (size_t)OUT_DIM * KDIM * 2;   // 4 MB bf16 W^T

  if (ws_size >= needA + needW) {
    unsigned short* Ag = (unsigned short*)d_ws;
    unsigned short* Wt = (unsigned short*)((char*)d_ws + needA);
    kan_prep<<<(BATCH * IN_DIM) / 256 + (IN_DIM * OUT_DIM) / 256, 256, 0, stream>>>(
        x, coeff, scaling, Ag, Wt);
    kan_gemm_p<<<(BATCH / 64) * (OUT_DIM / 64), 256, 0, stream>>>(Ag, Wt, out);
  } else {
    kan_gemm_fb<<<dim3(OUT_DIM / 64, BATCH / 64), 256, 0, stream>>>(x, coeff, scaling, out);
  }
}